// Round 15
// baseline (104.336 us; speedup 1.0000x reference)
//
#include <hip/hip_runtime.h>
#include <cstddef>
#include <cstdint>

constexpr int BATCH = 16;
constexpr int NQ    = 1024;
constexpr float QSCALE = 0.17677669529663687f * 1.4426950408889634f; // 32^-0.5 * log2e

typedef __attribute__((ext_vector_type(8))) short bf8;            // MFMA operand (8 bf16)
typedef __attribute__((ext_vector_type(4))) float f32x4;
typedef __attribute__((ext_vector_type(2))) unsigned short us2;
typedef __attribute__((ext_vector_type(4))) unsigned short us4;
typedef __attribute__((ext_vector_type(8))) unsigned short us8;

__device__ inline unsigned short f2bf(float x) {
  union { float f; uint32_t u; } c{x};
  uint32_t r = c.u + 0x7fffu + ((c.u >> 16) & 1u);   // RNE
  return (unsigned short)(r >> 16);
}
__device__ inline float b2f(unsigned short v) {
  union { uint32_t u; float f; } c{(uint32_t)v << 16};
  return c.f;
}
__device__ inline float fast_exp2(float x) {
#if __has_builtin(__builtin_amdgcn_exp2f)
  return __builtin_amdgcn_exp2f(x);
#else
  return exp2f(x);
#endif
}

// ---------------------------------------------------------------------------
// Weights -> bf16.
// ---------------------------------------------------------------------------
__global__ __launch_bounds__(256) void k_wcvt(const float* __restrict__ w1,
                                              const float* __restrict__ wq,
                                              const float* __restrict__ w2,
                                              unsigned short* __restrict__ o1,
                                              unsigned short* __restrict__ oq,
                                              unsigned short* __restrict__ o2) {
  int idx = (blockIdx.x * 256 + threadIdx.x) * 8;
  const float* s; unsigned short* d; int off;
  if (idx < 65536)        { s = w1; d = o1; off = idx; }
  else if (idx < 114688)  { s = wq; d = oq; off = idx - 65536; }
  else                    { s = w2; d = o2; off = idx - 114688; }
  float4 a = *(const float4*)(s + off);
  float4 b = *(const float4*)(s + off + 4);
  us8 o = {f2bf(a.x), f2bf(a.y), f2bf(a.z), f2bf(a.w),
           f2bf(b.x), f2bf(b.y), f2bf(b.z), f2bf(b.w)};
  *(us8*)(d + off) = o;
}

// ---------------------------------------------------------------------------
// conv1 (fused transpose + fused bn1 partial stats), 32n tile for occupancy.
// grid (32, 1, 16), 256 threads, 4 waves (each 32n x 32m), K=512 in 8 steps.
// ---------------------------------------------------------------------------
__global__ __launch_bounds__(256) void k_conv1(const float* __restrict__ x,
                                               const unsigned short* __restrict__ W,
                                               unsigned short* __restrict__ y1T,
                                               float* __restrict__ pS1,
                                               float* __restrict__ pQ1) {
  constexpr int BS = 68;
  __shared__ unsigned short Bl[32 * BS];
  __shared__ float Sl[128], Ql[128];

  const int bb = blockIdx.z;
  const int n0 = blockIdx.x * 32;
  const int tid = threadIdx.x, lane = tid & 63;
  const int wm = tid >> 6;
  const int i = lane & 15, g = lane >> 4;

  const int kb = tid >> 3;
  const int nb = tid & 7;

  f32x4 acc[2][2];
#pragma unroll
  for (int a = 0; a < 2; ++a)
#pragma unroll
    for (int b = 0; b < 2; ++b) acc[a][b] = {0.f, 0.f, 0.f, 0.f};

  float4 rv[2];
#pragma unroll
  for (int r = 0; r < 2; ++r)
    rv[r] = *(const float4*)(x + (((size_t)(bb * 512 + kb * 2 + r)) << 10) + n0 + nb * 4);

  for (int s = 0; s < 8; ++s) {
    bf8 wf[2][2];
#pragma unroll
    for (int b = 0; b < 2; ++b)
#pragma unroll
      for (int h = 0; h < 2; ++h)
        wf[b][h] = *(const bf8*)(W + (size_t)(wm * 32 + b * 16 + i) * 512 + s * 64 + h * 32 + g * 8);

    __syncthreads();
#pragma unroll
    for (int j = 0; j < 4; ++j) {
      us2 pk = {f2bf((&rv[0].x)[j]), f2bf((&rv[1].x)[j])};
      *(us2*)&Bl[(nb * 4 + j) * BS + kb * 2] = pk;
    }
    __syncthreads();

    if (s < 7) {
#pragma unroll
      for (int r = 0; r < 2; ++r)
        rv[r] = *(const float4*)(x + (((size_t)(bb * 512 + (s + 1) * 64 + kb * 2 + r)) << 10) + n0 + nb * 4);
    }

#pragma unroll
    for (int h = 0; h < 2; ++h) {
      bf8 af[2];
#pragma unroll
      for (int a = 0; a < 2; ++a)
        af[a] = *(const bf8*)&Bl[(a * 16 + i) * BS + h * 32 + g * 8];
#pragma unroll
      for (int a = 0; a < 2; ++a)
#pragma unroll
        for (int b = 0; b < 2; ++b)
          acc[a][b] = __builtin_amdgcn_mfma_f32_16x16x32_bf16(wf[b][h], af[a], acc[a][b], 0, 0, 0);
    }
  }

#pragma unroll
  for (int a = 0; a < 2; ++a)
#pragma unroll
    for (int b = 0; b < 2; ++b) {
      const int n = n0 + a * 16 + i;
      const int c = wm * 32 + b * 16 + 4 * g;
      us4 pk = {f2bf(acc[a][b][0]), f2bf(acc[a][b][1]), f2bf(acc[a][b][2]), f2bf(acc[a][b][3])};
      *(us4*)(y1T + ((size_t)(bb << 10) + n) * 128 + c) = pk;
    }

#pragma unroll
  for (int b = 0; b < 2; ++b) {
    float sb[4], qb[4];
#pragma unroll
    for (int r = 0; r < 4; ++r) {
      float v0 = b2f(f2bf(acc[0][b][r]));
      float v1 = b2f(f2bf(acc[1][b][r]));
      sb[r] = v0 + v1;
      qb[r] = v0 * v0 + v1 * v1;
    }
#pragma unroll
    for (int o = 1; o < 16; o <<= 1) {
#pragma unroll
      for (int r = 0; r < 4; ++r) {
        sb[r] += __shfl_xor(sb[r], o);
        qb[r] += __shfl_xor(qb[r], o);
      }
    }
    if (i == 0) {
#pragma unroll
      for (int r = 0; r < 4; ++r) {
        const int c = wm * 32 + b * 16 + 4 * g + r;
        Sl[c] = sb[r];
        Ql[c] = qb[r];
      }
    }
  }

  __syncthreads();
  const int blk = bb * 32 + blockIdx.x;      // 0..511
  if (tid < 128) {
    pS1[(size_t)tid * 512 + blk] = Sl[tid];
    pQ1[(size_t)tid * 512 + blk] = Ql[tid];
  }
}

// 128 blocks x 64 threads: reduce 512 partials per channel -> scl1/sht1.
__global__ __launch_bounds__(64) void k_bnfin1(const float* __restrict__ pS1,
                                               const float* __restrict__ pQ1,
                                               const float* __restrict__ g,
                                               const float* __restrict__ be,
                                               float* __restrict__ scl,
                                               float* __restrict__ sht) {
  const int c = blockIdx.x, t = threadIdx.x;
  float S = 0.f, Q = 0.f;
#pragma unroll
  for (int k = 0; k < 8; ++k) {
    S += pS1[(size_t)c * 512 + t + k * 64];
    Q += pQ1[(size_t)c * 512 + t + k * 64];
  }
#pragma unroll
  for (int o = 32; o > 0; o >>= 1) {
    S += __shfl_down(S, o);
    Q += __shfl_down(Q, o);
  }
  if (t == 0) {
    const float inv_n = 1.f / 16384.f;
    const float mean = S * inv_n, var = Q * inv_n - mean * mean;
    const float sc = rsqrtf(var + 1e-5f) * g[c];
    scl[c] = sc;
    sht[c] = be[c] - mean * sc;
  }
}

// ---------------------------------------------------------------------------
// qkv GEMM: stage y1T tile ONCE (bn1+relu fused), compute q,k,v against it.
// grid (8, 2, 16).
// ---------------------------------------------------------------------------
__global__ __launch_bounds__(256) void k_qkv(const unsigned short* __restrict__ W,
                                             const unsigned short* __restrict__ Bact,
                                             const float* __restrict__ scl,
                                             const float* __restrict__ sht,
                                             const float* __restrict__ rw,
                                             const float* __restrict__ rh,
                                             unsigned short* __restrict__ out0,
                                             unsigned short* __restrict__ out1,
                                             unsigned short* __restrict__ out2) {
  constexpr int BS = 136;
  __shared__ unsigned short Blds[128 * BS];
  __shared__ float scl_s[128], sht_s[128];

  const int bb = blockIdx.z, half = blockIdx.y;
  const int n0 = blockIdx.x * 128;
  const int tid = threadIdx.x, lane = tid & 63, wv = tid >> 6;
  const int wn = wv & 1, wm = wv >> 1;
  const int i = lane & 15, g = lane >> 4;

  const unsigned short* Bp = Bact + ((size_t)bb * NQ + n0) * 128;

  const int sn = tid >> 1;
  const int sk = (tid & 1) * 8;

  if (tid < 128) { scl_s[tid] = scl[tid]; sht_s[tid] = sht[tid]; }

  auto loadw = [&](bf8 (&wf)[2][4], int typ) {
    const int m0 = typ * 128 + half * 64;
#pragma unroll
    for (int b = 0; b < 2; ++b)
#pragma unroll
      for (int h = 0; h < 4; ++h)
        wf[b][h] = *(const bf8*)(W + (size_t)(m0 + wm * 32 + b * 16 + i) * 128 + h * 32 + g * 8);
  };

  bf8 wf0[2][4], wf1[2][4];
  loadw(wf0, 0);
  __syncthreads();

#pragma unroll
  for (int p = 0; p < 8; ++p) {
    us8 v = *(const us8*)(Bp + (size_t)sn * 128 + sk + p * 16);
    const int kb = sk + p * 16;
    float scv[8], shv[8];
    *(float4*)scv = *(const float4*)&scl_s[kb];
    *(float4*)(scv + 4) = *(const float4*)&scl_s[kb + 4];
    *(float4*)shv = *(const float4*)&sht_s[kb];
    *(float4*)(shv + 4) = *(const float4*)&sht_s[kb + 4];
#pragma unroll
    for (int j = 0; j < 8; ++j)
      v[j] = f2bf(fmaxf(fmaf(b2f(v[j]), scv[j], shv[j]), 0.f));
    *(us8*)(&Blds[sn * BS + sk + p * 16]) = v;
  }
  __syncthreads();

  f32x4 acc[4][2];

  auto gemmWA = [&](bf8 (&wf)[2][4]) {
#pragma unroll
    for (int a = 0; a < 4; ++a)
#pragma unroll
      for (int b = 0; b < 2; ++b) acc[a][b] = {0.f, 0.f, 0.f, 0.f};
#pragma unroll
    for (int h = 0; h < 4; ++h) {
      bf8 af[4];
#pragma unroll
      for (int a = 0; a < 4; ++a)
        af[a] = *(const bf8*)&Blds[(wn * 64 + a * 16 + i) * BS + h * 32 + g * 8];
#pragma unroll
      for (int a = 0; a < 4; ++a)
#pragma unroll
        for (int b = 0; b < 2; ++b)
          acc[a][b] = __builtin_amdgcn_mfma_f32_16x16x32_bf16(wf[b][h], af[a], acc[a][b], 0, 0, 0);
    }
  };
  auto gemmAW = [&](bf8 (&wf)[2][4]) {
#pragma unroll
    for (int a = 0; a < 4; ++a)
#pragma unroll
      for (int b = 0; b < 2; ++b) acc[a][b] = {0.f, 0.f, 0.f, 0.f};
#pragma unroll
    for (int h = 0; h < 4; ++h) {
      bf8 af[4];
#pragma unroll
      for (int a = 0; a < 4; ++a)
        af[a] = *(const bf8*)&Blds[(wn * 64 + a * 16 + i) * BS + h * 32 + g * 8];
#pragma unroll
      for (int a = 0; a < 4; ++a)
#pragma unroll
        for (int b = 0; b < 2; ++b)
          acc[a][b] = __builtin_amdgcn_mfma_f32_16x16x32_bf16(af[a], wf[b][h], acc[a][b], 0, 0, 0);
    }
  };

  // ---- q ----
  loadw(wf1, 1);
  gemmWA(wf0);
#pragma unroll
  for (int a = 0; a < 4; ++a)
#pragma unroll
    for (int b = 0; b < 2; ++b) {
      const int n = n0 + wn * 64 + a * 16 + i;
      const int c = half * 64 + wm * 32 + b * 16 + 4 * g;
      const int hh = c >> 5, d = c & 31;
      us4 pk = {f2bf(acc[a][b][0] * QSCALE), f2bf(acc[a][b][1] * QSCALE),
                f2bf(acc[a][b][2] * QSCALE), f2bf(acc[a][b][3] * QSCALE)};
      *(us4*)(out0 + (((size_t)(bb * 4 + hh) << 10) + n) * 32 + d) = pk;
    }

  // ---- k ----
  loadw(wf0, 2);
  gemmWA(wf1);
#pragma unroll
  for (int a = 0; a < 4; ++a)
#pragma unroll
    for (int b = 0; b < 2; ++b) {
      const int n = n0 + wn * 64 + a * 16 + i;
      const int c = half * 64 + wm * 32 + b * 16 + 4 * g;
      const int hh = c >> 5, d = c & 31;
      const int wcol = n & 31, hrow = n >> 5;
      float vv[4];
#pragma unroll
      for (int r = 0; r < 4; ++r)
        vv[r] = acc[a][b][r] + rw[(c + r) * 32 + wcol] + rh[(c + r) * 32 + hrow];
      us4 pk = {f2bf(vv[0]), f2bf(vv[1]), f2bf(vv[2]), f2bf(vv[3])};
      *(us4*)(out1 + (((size_t)(bb * 4 + hh) << 10) + n) * 32 + d) = pk;
    }

  // ---- v ----
  gemmAW(wf0);
#pragma unroll
  for (int a = 0; a < 4; ++a)
#pragma unroll
    for (int b = 0; b < 2; ++b) {
      const int c = half * 64 + wm * 32 + b * 16 + i;
      const int nb = n0 + wn * 64 + a * 16 + 4 * g;
      const int hh = c >> 5, dd = c & 31;
      us4 pk = {f2bf(acc[a][b][0]), f2bf(acc[a][b][1]), f2bf(acc[a][b][2]), f2bf(acc[a][b][3])};
      *(us4*)(out2 + (((size_t)(bb * 4 + hh) * 32 + dd) << 10) + nb) = pk;
    }
}

// ---------------------------------------------------------------------------
// MFMA flash attention, KV-split, double-buffered LDS (1 barrier/tile) +
// setprio around MFMA clusters. grid (NQ/128, 64, 2), 256 threads.
// Emits unnormalized partials po[(part*64+bh)][n][32] fp32 + pm/pl.
// ---------------------------------------------------------------------------
__global__ __launch_bounds__(256) void k_attn_part(const unsigned short* __restrict__ qs,
                                                   const unsigned short* __restrict__ kt,
                                                   const unsigned short* __restrict__ vt,
                                                   float* __restrict__ po,
                                                   float* __restrict__ pm,
                                                   float* __restrict__ pl) {
  const int bh   = blockIdx.y;
  const int part = blockIdx.z;
  const int tid  = threadIdx.x;
  const int lane = tid & 63;
  const int wv   = tid >> 6;
  const int i    = lane & 15;
  const int g    = lane >> 4;
  const int n0w  = blockIdx.x * 128 + wv * 32;

  __shared__ unsigned short Ks[2][64 * 56];
  __shared__ unsigned short Vt[2][32 * 72];

  const bf8 qfA = *(const bf8*)(qs + ((size_t)bh * NQ + n0w + i) * 32 + g * 8);
  const bf8 qfB = *(const bf8*)(qs + ((size_t)bh * NQ + n0w + 16 + i) * 32 + g * 8);

  f32x4 o0A = {0.f,0.f,0.f,0.f}, o1A = {0.f,0.f,0.f,0.f};
  f32x4 o0B = {0.f,0.f,0.f,0.f}, o1B = {0.f,0.f,0.f,0.f};
  float mA = -1e30f, lA = 0.f, mB = -1e30f, lB = 0.f;

  const unsigned short* kb = kt + (size_t)bh * NQ * 32;
  const unsigned short* vb = vt + (size_t)bh * 32 * NQ;

  const int skey = tid >> 2, sds = (tid & 3) * 8;
  const int svd  = tid >> 3, svn = (tid & 7) * 8;

  const int kbeg = part * 512;

  // prologue: stage tile 0 into buffer 0
  bf8 kvld = *(const bf8*)(kb + (size_t)(kbeg + skey) * 32 + sds);
  bf8 vvld = *(const bf8*)(vb + (size_t)svd * NQ + kbeg + svn);
  *(bf8*)&Ks[0][skey * 56 + sds] = kvld;
  *(bf8*)&Vt[0][svd * 72 + svn]  = vvld;
  __syncthreads();

  for (int it = 0; it < 8; ++it) {
    const int cur = it & 1, nxt = cur ^ 1;
    if (it < 7) {     // issue next-tile loads; latency hides under compute
      const int k0n = kbeg + (it + 1) * 64;
      kvld = *(const bf8*)(kb + (size_t)(k0n + skey) * 32 + sds);
      vvld = *(const bf8*)(vb + (size_t)svd * NQ + k0n + svn);
    }

    const f32x4 zero = {0.f,0.f,0.f,0.f};
    f32x4 stA[4], stB[4];
    __builtin_amdgcn_s_setprio(1);
#pragma unroll
    for (int t = 0; t < 4; ++t) {
      bf8 kf = *(const bf8*)&Ks[cur][(t * 16 + i) * 56 + g * 8];
      stA[t] = __builtin_amdgcn_mfma_f32_16x16x32_bf16(kf, qfA, zero, 0, 0, 0);
      stB[t] = __builtin_amdgcn_mfma_f32_16x16x32_bf16(kf, qfB, zero, 0, 0, 0);
    }
    __builtin_amdgcn_s_setprio(0);

    unsigned int pkA[4][2], pkB[4][2];
    {
      float tmax = stA[0][0];
#pragma unroll
      for (int t = 0; t < 4; ++t)
#pragma unroll
        for (int r = 0; r < 4; ++r) tmax = fmaxf(tmax, stA[t][r]);
      tmax = fmaxf(tmax, __shfl_xor(tmax, 16));
      tmax = fmaxf(tmax, __shfl_xor(tmax, 32));
      const float mn = fmaxf(mA, tmax);
      const float corr = fast_exp2(mA - mn);
      mA = mn;
      float ps = 0.f;
#pragma unroll
      for (int t = 0; t < 4; ++t) {
        float p0 = fast_exp2(stA[t][0] - mn);
        float p1 = fast_exp2(stA[t][1] - mn);
        float p2 = fast_exp2(stA[t][2] - mn);
        float p3 = fast_exp2(stA[t][3] - mn);
        ps += (p0 + p1) + (p2 + p3);
        unsigned int pa, pb;
        asm("v_cvt_pk_bf16_f32 %0, %1, %2" : "=v"(pa) : "v"(p0), "v"(p1));
        asm("v_cvt_pk_bf16_f32 %0, %1, %2" : "=v"(pb) : "v"(p2), "v"(p3));
        pkA[t][0] = pa; pkA[t][1] = pb;
      }
      ps += __shfl_xor(ps, 16);
      ps += __shfl_xor(ps, 32);
      lA = lA * corr + ps;
#pragma unroll
      for (int r = 0; r < 4; ++r) { o0A[r] *= corr; o1A[r] *= corr; }
    }
    {
      float tmax = stB[0][0];
#pragma unroll
      for (int t = 0; t < 4; ++t)
#pragma unroll
        for (int r = 0; r < 4; ++r) tmax = fmaxf(tmax, stB[t][r]);
      tmax = fmaxf(tmax, __shfl_xor(tmax, 16));
      tmax = fmaxf(tmax, __shfl_xor(tmax, 32));
      const float mn = fmaxf(mB, tmax);
      const float corr = fast_exp2(mB - mn);
      mB = mn;
      float ps = 0.f;
#pragma unroll
      for (int t = 0; t < 4; ++t) {
        float p0 = fast_exp2(stB[t][0] - mn);
        float p1 = fast_exp2(stB[t][1] - mn);
        float p2 = fast_exp2(stB[t][2] - mn);
        float p3 = fast_exp2(stB[t][3] - mn);
        ps += (p0 + p1) + (p2 + p3);
        unsigned int pa, pb;
        asm("v_cvt_pk_bf16_f32 %0, %1, %2" : "=v"(pa) : "v"(p0), "v"(p1));
        asm("v_cvt_pk_bf16_f32 %0, %1, %2" : "=v"(pb) : "v"(p2), "v"(p3));
        pkB[t][0] = pa; pkB[t][1] = pb;
      }
      ps += __shfl_xor(ps, 16);
      ps += __shfl_xor(ps, 32);
      lB = lB * corr + ps;
#pragma unroll
      for (int r = 0; r < 4; ++r) { o0B[r] *= corr; o1B[r] *= corr; }
    }

    const int src0 = ((g & 1) << 5) + i;
    const int src1 = src0 + 16;
    const bool hi = (g >= 2);
    __builtin_amdgcn_s_setprio(1);
#pragma unroll
    for (int s = 0; s < 2; ++s) {
      int a0 = __shfl((int)pkA[2 * s][0], src0);
      int a1 = __shfl((int)pkA[2 * s][1], src0);
      int a2 = __shfl((int)pkA[2 * s][0], src1);
      int a3 = __shfl((int)pkA[2 * s][1], src1);
      int b0 = __shfl((int)pkA[2 * s + 1][0], src0);
      int b1 = __shfl((int)pkA[2 * s + 1][1], src0);
      int b2 = __shfl((int)pkA[2 * s + 1][0], src1);
      int b3 = __shfl((int)pkA[2 * s + 1][1], src1);
      union { int d[4]; bf8 v; } pfA;
      pfA.d[0] = hi ? b0 : a0;
      pfA.d[1] = hi ? b1 : a1;
      pfA.d[2] = hi ? b2 : a2;
      pfA.d[3] = hi ? b3 : a3;
      int c0 = __shfl((int)pkB[2 * s][0], src0);
      int c1 = __shfl((int)pkB[2 * s][1], src0);
      int c2 = __shfl((int)pkB[2 * s][0], src1);
      int c3 = __shfl((int)pkB[2 * s][1], src1);
      int d0 = __shfl((int)pkB[2 * s + 1][0], src0);
      int d1 = __shfl((int)pkB[2 * s + 1][1], src0);
      int d2 = __shfl((int)pkB[2 * s + 1][0], src1);
      int d3 = __shfl((int)pkB[2 * s + 1][1], src1);
      union { int d[4]; bf8 v; } pfB;
      pfB.d[0] = hi ? d0 : c0;
      pfB.d[1] = hi ? d1 : c1;
      pfB.d[2] = hi ? d2 : c2;
      pfB.d[3] = hi ? d3 : c3;
      bf8 vf0 = *(const bf8*)&Vt[cur][(i)      * 72 + s * 32 + g * 8];
      bf8 vf1 = *(const bf8*)&Vt[cur][(16 + i) * 72 + s * 32 + g * 8];
      o0A = __builtin_amdgcn_mfma_f32_16x16x32_bf16(vf0, pfA.v, o0A, 0, 0, 0);
      o1A = __builtin_amdgcn_mfma_f32_16x16x32_bf16(vf1, pfA.v, o1A, 0, 0, 0);
      o0B = __builtin_amdgcn_mfma_f32_16x16x32_bf16(vf0, pfB.v, o0B, 0, 0, 0);
      o1B = __builtin_amdgcn_mfma_f32_16x16x32_bf16(vf1, pfB.v, o1B, 0, 0, 0);
    }
    __builtin_amdgcn_s_setprio(0);

    if (it < 7) {   // write next tile into the other buffer; one barrier/iter
      *(bf8*)&Ks[nxt][skey * 56 + sds] = kvld;
      *(bf8*)&Vt[nxt][svd * 72 + svn]  = vvld;
    }
    __syncthreads();
  }

  const size_t pb = ((size_t)(part * 64 + bh) << 10);
  float* dA = po + (pb + n0w + i) * 32 + 4 * g;
  float* dB = po + (pb + n0w + 16 + i) * 32 + 4 * g;
  *(f32x4*)dA        = o0A;
  *(f32x4*)(dA + 16) = o1A;
  *(f32x4*)dB        = o0B;
  *(f32x4*)(dB + 16) = o1B;
  if (g == 0) {
    pm[pb + n0w + i]      = mA;
    pl[pb + n0w + i]      = lA;
    pm[pb + n0w + 16 + i] = mB;
    pl[pb + n0w + 16 + i] = lB;
  }
}

// ---------------------------------------------------------------------------
// conv2 stats pass with FUSED attention combine in staging. grid (16, 2, 16).
// Thread (sn = tid>>2, h = tid&3) stages the 32-d head-h chunk of query n.
// ---------------------------------------------------------------------------
__global__ __launch_bounds__(256) void k_stat2(const unsigned short* __restrict__ W,
                                               const float* __restrict__ po,
                                               const float* __restrict__ pm,
                                               const float* __restrict__ pl,
                                               float* __restrict__ pBS,
                                               float* __restrict__ pBQ) {
  constexpr int BS = 264;
  __shared__ unsigned short Blds[64 * BS];
  __shared__ float Sl[256], Ql[256];
  const int bb = blockIdx.z;
  const int mh = blockIdx.y;
  const int n0 = blockIdx.x * 64;
  const int tid = threadIdx.x, lane = tid & 63, wv = tid >> 6;
  const int wn = wv & 1, wm = wv >> 1;
  const int i = lane & 15, g = lane >> 4;

  Sl[tid] = 0.f; Ql[tid] = 0.f;

  // staging with fused 2-part combine
  {
    const int sn = tid >> 2, sk = (tid & 3) * 32;
    const int h  = tid & 3;
    const int n  = n0 + sn;
    const size_t q0 = (((size_t)(bb * 4 + h)) << 10) + n;
    const size_t q1 = (((size_t)(64 + bb * 4 + h)) << 10) + n;
    const float m0 = pm[q0], m1 = pm[q1];
    const float l0 = pl[q0], l1 = pl[q1];
    const float M  = fmaxf(m0, m1);
    const float w0 = fast_exp2(m0 - M);
    const float w1 = fast_exp2(m1 - M);
    const float inv = 1.f / (w0 * l0 + w1 * l1);
    const float c0 = w0 * inv, c1 = w1 * inv;
    const float* s0 = po + q0 * 32;
    const float* s1 = po + q1 * 32;
#pragma unroll
    for (int p = 0; p < 4; ++p) {
      f32x4 a0 = *(const f32x4*)(s0 + p * 8);
      f32x4 a1 = *(const f32x4*)(s0 + p * 8 + 4);
      f32x4 b0 = *(const f32x4*)(s1 + p * 8);
      f32x4 b1 = *(const f32x4*)(s1 + p * 8 + 4);
      float fv[8];
#pragma unroll
      for (int r = 0; r < 4; ++r) {
        fv[r]     = a0[r] * c0 + b0[r] * c1;
        fv[4 + r] = a1[r] * c0 + b1[r] * c1;
      }
      us8 hi, lo;
#pragma unroll
      for (int j = 0; j < 8; ++j) {
        unsigned short h16 = f2bf(fv[j]);
        hi[j] = h16;
        lo[j] = f2bf(fv[j] - b2f(h16));
      }
      *(us8*)&Blds[sn * BS + sk + p * 8]       = hi;
      *(us8*)&Blds[sn * BS + 128 + sk + p * 8] = lo;
    }
  }
  __syncthreads();

  auto loadw = [&](bf8 (&wf)[2][4], int lp) {
    const int mt = mh * 4 + lp;
#pragma unroll
    for (int b = 0; b < 2; ++b)
#pragma unroll
      for (int h = 0; h < 4; ++h)
        wf[b][h] = *(const bf8*)(W + (size_t)(mt * 64 + wm * 32 + b * 16 + i) * 128 + h * 32 + g * 8);
  };

  auto step = [&](bf8 (&wf)[2][4], int lp) {
    f32x4 acc[2][2];
#pragma unroll
    for (int a = 0; a < 2; ++a)
#pragma unroll
      for (int b = 0; b < 2; ++b) acc[a][b] = {0.f, 0.f, 0.f, 0.f};
#pragma unroll
    for (int h = 0; h < 4; ++h) {
      bf8 ah[2], al[2];
#pragma unroll
      for (int a = 0; a < 2; ++a) {
        ah[a] = *(const bf8*)&Blds[(wn * 32 + a * 16 + i) * BS + h * 32 + g * 8];
        al[a] = *(const bf8*)&Blds[(wn * 32 + a * 16 + i) * BS + 128 + h * 32 + g * 8];
      }
#pragma unroll
      for (int a = 0; a < 2; ++a)
#pragma unroll
        for (int b = 0; b < 2; ++b) {
          acc[a][b] = __builtin_amdgcn_mfma_f32_16x16x32_bf16(ah[a], wf[b][h], acc[a][b], 0, 0, 0);
          acc[a][b] = __builtin_amdgcn_mfma_f32_16x16x32_bf16(al[a], wf[b][h], acc[a][b], 0, 0, 0);
        }
    }
#pragma unroll
    for (int b = 0; b < 2; ++b) {
      float s = 0.f, q = 0.f;
#pragma unroll
      for (int a = 0; a < 2; ++a)
#pragma unroll
        for (int r = 0; r < 4; ++r) {
          float v = acc[a][b][r];
          s += v; q += v * v;
        }
      s += __shfl_xor(s, 16); s += __shfl_xor(s, 32);
      q += __shfl_xor(q, 16); q += __shfl_xor(q, 32);
      if ((lane & 48) == 0) {
        const int cl = lp * 64 + wm * 32 + b * 16 + i;
        atomicAdd(&Sl[cl], s);
        atomicAdd(&Ql[cl], q);
      }
    }
  };

  bf8 wfA[2][4], wfB[2][4];
  loadw(wfA, 0);
  loadw(wfB, 1);
  step(wfA, 0);
  loadw(wfA, 2);
  step(wfB, 1);
  loadw(wfB, 3);
  step(wfA, 2);
  step(wfB, 3);

  __syncthreads();
  const int pidx = bb * 16 + blockIdx.x;
  pBS[(size_t)(mh * 256 + tid) * 256 + pidx] = Sl[tid];
  pBQ[(size_t)(mh * 256 + tid) * 256 + pidx] = Ql[tid];
}

// 512 blocks x 64 threads: reduce 256 partials per channel.
__global__ __launch_bounds__(64) void k_bnfin2(const float* __restrict__ pBS,
                                               const float* __restrict__ pBQ,
                                               const float* __restrict__ g,
                                               const float* __restrict__ be,
                                               float* __restrict__ scl,
                                               float* __restrict__ sht) {
  const int c = blockIdx.x, t = threadIdx.x;
  float S = 0.f, Q = 0.f;
#pragma unroll
  for (int k = 0; k < 4; ++k) {
    S += pBS[(size_t)c * 256 + t + k * 64];
    Q += pBQ[(size_t)c * 256 + t + k * 64];
  }
#pragma unroll
  for (int o = 32; o > 0; o >>= 1) {
    S += __shfl_down(S, o);
    Q += __shfl_down(Q, o);
  }
  if (t == 0) {
    const float inv_n = 1.f / 16384.f;
    const float mean = S * inv_n, var = Q * inv_n - mean * mean;
    const float sc = rsqrtf(var + 1e-5f) * g[c];
    scl[c] = sc;
    sht[c] = be[c] - mean * sc;
  }
}

// ---------------------------------------------------------------------------
// final pass: staging (same fused combine, identical fp32 math as k_stat2),
// recompute conv2, apply bn2 + residual + relu. grid (16, 2, 16).
// ---------------------------------------------------------------------------
__global__ __launch_bounds__(256) void k_final2(const unsigned short* __restrict__ W,
                                                const float* __restrict__ po,
                                                const float* __restrict__ pm,
                                                const float* __restrict__ pl,
                                                const float* __restrict__ x,
                                                const float* __restrict__ scl2,
                                                const float* __restrict__ sht2,
                                                float* __restrict__ out) {
  constexpr int BS = 264;
  __shared__ unsigned short Blds[64 * BS];
  __shared__ float scl_s[256], sht_s[256];
  const int bb = blockIdx.z;
  const int mh = blockIdx.y;
  const int n0 = blockIdx.x * 64;
  const int tid = threadIdx.x, lane = tid & 63, wv = tid >> 6;
  const int wn = wv & 1, wm = wv >> 1;
  const int i = lane & 15, g = lane >> 4;

  scl_s[tid] = scl2[mh * 256 + tid];
  sht_s[tid] = sht2[mh * 256 + tid];

  {
    const int sn = tid >> 2, sk = (tid & 3) * 32;
    const int h  = tid & 3;
    const int n  = n0 + sn;
    const size_t q0 = (((size_t)(bb * 4 + h)) << 10) + n;
    const size_t q1 = (((size_t)(64 + bb * 4 + h)) << 10) + n;
    const float m0 = pm[q0], m1 = pm[q1];
    const float l0 = pl[q0], l1 = pl[q1];
    const float M  = fmaxf(m0, m1);
    const float w0 = fast_exp2(m0 - M);
    const float w1 = fast_exp2(m1 - M);
    const float inv = 1.f / (w0 * l0 + w1 * l1);
    const float c0 = w0 * inv, c1 = w1 * inv;
    const float* s0 = po + q0 * 32;
    const float* s1 = po + q1 * 32;
#pragma unroll
    for (int p = 0; p < 4; ++p) {
      f32x4 a0 = *(const f32x4*)(s0 + p * 8);
      f32x4 a1 = *(const f32x4*)(s0 + p * 8 + 4);
      f32x4 b0 = *(const f32x4*)(s1 + p * 8);
      f32x4 b1 = *(const f32x4*)(s1 + p * 8 + 4);
      float fv[8];
#pragma unroll
      for (int r = 0; r < 4; ++r) {
        fv[r]     = a0[r] * c0 + b0[r] * c1;
        fv[4 + r] = a1[r] * c0 + b1[r] * c1;
      }
      us8 hi, lo;
#pragma unroll
      for (int j = 0; j < 8; ++j) {
        unsigned short h16 = f2bf(fv[j]);
        hi[j] = h16;
        lo[j] = f2bf(fv[j] - b2f(h16));
      }
      *(us8*)&Blds[sn * BS + sk + p * 8]       = hi;
      *(us8*)&Blds[sn * BS + 128 + sk + p * 8] = lo;
    }
  }
  __syncthreads();

  auto loadw = [&](bf8 (&wf)[2][4], int lp) {
    const int mt = mh * 4 + lp;
#pragma unroll
    for (int b = 0; b < 2; ++b)
#pragma unroll
      for (int h = 0; h < 4; ++h)
        wf[b][h] = *(const bf8*)(W + (size_t)(mt * 64 + wm * 32 + b * 16 + i) * 128 + h * 32 + g * 8);
  };

  auto step = [&](bf8 (&wf)[2][4], int lp) {
    const int mt = mh * 4 + lp;
    f32x4 acc[2][2];
#pragma unroll
    for (int a = 0; a < 2; ++a)
#pragma unroll
      for (int b = 0; b < 2; ++b) acc[a][b] = {0.f, 0.f, 0.f, 0.f};
#pragma unroll
    for (int h = 0; h < 4; ++h) {
      bf8 ah[2], al[2];
#pragma unroll
      for (int a = 0; a < 2; ++a) {
        ah[a] = *(const bf8*)&Blds[(wn * 32 + a * 16 + i) * BS + h * 32 + g * 8];
        al[a] = *(const bf8*)&Blds[(wn * 32 + a * 16 + i) * BS + 128 + h * 32 + g * 8];
      }
#pragma unroll
      for (int a = 0; a < 2; ++a)
#pragma unroll
        for (int b = 0; b < 2; ++b) {
          acc[a][b] = __builtin_amdgcn_mfma_f32_16x16x32_bf16(ah[a], wf[b][h], acc[a][b], 0, 0, 0);
          acc[a][b] = __builtin_amdgcn_mfma_f32_16x16x32_bf16(al[a], wf[b][h], acc[a][b], 0, 0, 0);
        }
    }
#pragma unroll
    for (int a = 0; a < 2; ++a)
#pragma unroll
      for (int b = 0; b < 2; ++b) {
        const int c = mt * 64 + wm * 32 + b * 16 + i;
        const int cl = lp * 64 + wm * 32 + b * 16 + i;
        const int nb = n0 + wn * 32 + a * 16 + 4 * g;
        const float sc = scl_s[cl], sh = sht_s[cl];
        const size_t off = (((size_t)(bb * 512 + c)) << 10) + nb;
        float4 xv = *(const float4*)(x + off);
        f32x4 o;
        o[0] = fmaxf(acc[a][b][0] * sc + sh + xv.x, 0.f);
        o[1] = fmaxf(acc[a][b][1] * sc + sh + xv.y, 0.f);
        o[2] = fmaxf(acc[a][b][2] * sc + sh + xv.z, 0.f);
        o[3] = fmaxf(acc[a][b][3] * sc + sh + xv.w, 0.f);
        *(f32x4*)(out + off) = o;
      }
  };

  bf8 wfA[2][4], wfB[2][4];
  loadw(wfA, 0);
  loadw(wfB, 1);
  step(wfA, 0);
  loadw(wfA, 2);
  step(wfB, 1);
  loadw(wfB, 3);
  step(wfA, 2);
  step(wfB, 3);
}

// ---------------------------------------------------------------------------
extern "C" void kernel_launch(void* const* d_in, const int* in_sizes, int n_in,
                              void* d_out, int out_size, void* d_ws, size_t ws_size,
                              hipStream_t stream) {
  (void)in_sizes; (void)n_in; (void)out_size; (void)ws_size;
  const float* x    = (const float*)d_in[0];
  const float* w1   = (const float*)d_in[1];
  const float* g1   = (const float*)d_in[2];
  const float* b1   = (const float*)d_in[3];
  const float* wqkv = (const float*)d_in[4];
  const float* rw   = (const float*)d_in[5];
  const float* rh   = (const float*)d_in[6];
  const float* w2   = (const float*)d_in[7];
  const float* g2   = (const float*)d_in[8];
  const float* b2   = (const float*)d_in[9];
  float* out = (float*)d_out;
  char* base = (char*)d_ws;

  // Workspace (bytes): y1T [8,12) | qs [12,16) | kt [16,20) | vt [20,24)
  // | weights [24M,+352K) | partials/scalars [25M..26.7M)
  // | po fp32 [32M,48M) | pm [48M,+512K) | pl [48.5M,+512K)
  unsigned short* y1T = (unsigned short*)(base + (8u  << 20));
  unsigned short* qs  = (unsigned short*)(base + (12u << 20));
  unsigned short* kt  = (unsigned short*)(base + (16u << 20));
  unsigned short* vt  = (unsigned short*)(base + (20u << 20));
  unsigned short* wb1 = (unsigned short*)(base + (24u << 20));
  unsigned short* wbq = wb1 + 65536;
  unsigned short* wb2 = wbq + 49152;
  float* pS1  = (float*)(base + (25u << 20));  // 128*512
  float* pQ1  = pS1 + 65536;
  float* pBS  = pQ1 + 65536;                   // 512*256
  float* pBQ  = pBS + 131072;
  float* scl1 = pBQ + 131072;
  float* sht1 = scl1 + 128;
  float* scl2 = sht1 + 128;
  float* sht2 = scl2 + 512;
  float* po   = (float*)(base + (32u << 20));  // 2*64*1024*32 fp32 = 16MB
  float* pm   = (float*)(base + (48u << 20));  // 2*64*1024
  float* pl   = pm + 131072;

  // 1) weights -> bf16
  k_wcvt<<<88, 256, 0, stream>>>(w1, wqkv, w2, wb1, wbq, wb2);
  // 2) conv1 (fused transpose + bn1 partials)
  k_conv1<<<dim3(32, 1, BATCH), 256, 0, stream>>>(x, wb1, y1T, pS1, pQ1);
  // 3) bn1 finalize
  k_bnfin1<<<128, 64, 0, stream>>>(pS1, pQ1, g1, b1, scl1, sht1);
  // 4) qkv (MFMA, bn1+relu fused, single-staged) -> q,k'(+r),v bf16
  k_qkv<<<dim3(8, 2, BATCH), 256, 0, stream>>>(wbq, y1T, scl1, sht1,
                                               rw, rh, qs, kt, vt);
  // 5) flash attention partials (double-buffered, 1 barrier/tile, setprio)
  k_attn_part<<<dim3(NQ / 128, BATCH * 4, 2), 256, 0, stream>>>(qs, kt, vt, po, pm, pl);
  // 6) conv2 stats pass (fused combine in staging) -> pBS/pBQ
  k_stat2<<<dim3(16, 2, BATCH), 256, 0, stream>>>(wb2, po, pm, pl, pBS, pBQ);
  // 7) bn2 finalize
  k_bnfin2<<<512, 64, 0, stream>>>(pBS, pBQ, g2, b2, scl2, sht2);
  // 8) final: fused combine + recompute conv2 + bn2 + residual + relu -> out
  k_final2<<<dim3(16, 2, BATCH), 256, 0, stream>>>(wb2, po, pm, pl, x, scl2, sht2, out);
}

// Round 16
// 101.240 us; speedup vs baseline: 1.0306x; 1.0306x over previous
//
#include <hip/hip_runtime.h>
#include <cstddef>
#include <cstdint>

constexpr int BATCH = 16;
constexpr int NQ    = 1024;
constexpr float QSCALE = 0.17677669529663687f * 1.4426950408889634f; // 32^-0.5 * log2e

typedef __attribute__((ext_vector_type(8))) short bf8;            // MFMA operand (8 bf16)
typedef __attribute__((ext_vector_type(4))) float f32x4;
typedef __attribute__((ext_vector_type(2))) unsigned short us2;
typedef __attribute__((ext_vector_type(4))) unsigned short us4;
typedef __attribute__((ext_vector_type(8))) unsigned short us8;

__device__ inline unsigned short f2bf(float x) {
  union { float f; uint32_t u; } c{x};
  uint32_t r = c.u + 0x7fffu + ((c.u >> 16) & 1u);   // RNE
  return (unsigned short)(r >> 16);
}
__device__ inline float b2f(unsigned short v) {
  union { uint32_t u; float f; } c{(uint32_t)v << 16};
  return c.f;
}
__device__ inline float fast_exp2(float x) {
#if __has_builtin(__builtin_amdgcn_exp2f)
  return __builtin_amdgcn_exp2f(x);
#else
  return exp2f(x);
#endif
}

// ---------------------------------------------------------------------------
// Weights -> bf16.
// ---------------------------------------------------------------------------
__global__ __launch_bounds__(256) void k_wcvt(const float* __restrict__ w1,
                                              const float* __restrict__ wq,
                                              const float* __restrict__ w2,
                                              unsigned short* __restrict__ o1,
                                              unsigned short* __restrict__ oq,
                                              unsigned short* __restrict__ o2) {
  int idx = (blockIdx.x * 256 + threadIdx.x) * 8;
  const float* s; unsigned short* d; int off;
  if (idx < 65536)        { s = w1; d = o1; off = idx; }
  else if (idx < 114688)  { s = wq; d = oq; off = idx - 65536; }
  else                    { s = w2; d = o2; off = idx - 114688; }
  float4 a = *(const float4*)(s + off);
  float4 b = *(const float4*)(s + off + 4);
  us8 o = {f2bf(a.x), f2bf(a.y), f2bf(a.z), f2bf(a.w),
           f2bf(b.x), f2bf(b.y), f2bf(b.z), f2bf(b.w)};
  *(us8*)(d + off) = o;
}

// ---------------------------------------------------------------------------
// conv1 (fused transpose + fused bn1 partial stats), 32n tile for occupancy.
// grid (32, 1, 16), 256 threads, 4 waves (each 32n x 32m), K=512 in 8 steps.
// ---------------------------------------------------------------------------
__global__ __launch_bounds__(256) void k_conv1(const float* __restrict__ x,
                                               const unsigned short* __restrict__ W,
                                               unsigned short* __restrict__ y1T,
                                               float* __restrict__ pS1,
                                               float* __restrict__ pQ1) {
  constexpr int BS = 68;
  __shared__ unsigned short Bl[32 * BS];
  __shared__ float Sl[128], Ql[128];

  const int bb = blockIdx.z;
  const int n0 = blockIdx.x * 32;
  const int tid = threadIdx.x, lane = tid & 63;
  const int wm = tid >> 6;
  const int i = lane & 15, g = lane >> 4;

  const int kb = tid >> 3;
  const int nb = tid & 7;

  f32x4 acc[2][2];
#pragma unroll
  for (int a = 0; a < 2; ++a)
#pragma unroll
    for (int b = 0; b < 2; ++b) acc[a][b] = {0.f, 0.f, 0.f, 0.f};

  float4 rv[2];
#pragma unroll
  for (int r = 0; r < 2; ++r)
    rv[r] = *(const float4*)(x + (((size_t)(bb * 512 + kb * 2 + r)) << 10) + n0 + nb * 4);

  for (int s = 0; s < 8; ++s) {
    bf8 wf[2][2];
#pragma unroll
    for (int b = 0; b < 2; ++b)
#pragma unroll
      for (int h = 0; h < 2; ++h)
        wf[b][h] = *(const bf8*)(W + (size_t)(wm * 32 + b * 16 + i) * 512 + s * 64 + h * 32 + g * 8);

    __syncthreads();
#pragma unroll
    for (int j = 0; j < 4; ++j) {
      us2 pk = {f2bf((&rv[0].x)[j]), f2bf((&rv[1].x)[j])};
      *(us2*)&Bl[(nb * 4 + j) * BS + kb * 2] = pk;
    }
    __syncthreads();

    if (s < 7) {
#pragma unroll
      for (int r = 0; r < 2; ++r)
        rv[r] = *(const float4*)(x + (((size_t)(bb * 512 + (s + 1) * 64 + kb * 2 + r)) << 10) + n0 + nb * 4);
    }

#pragma unroll
    for (int h = 0; h < 2; ++h) {
      bf8 af[2];
#pragma unroll
      for (int a = 0; a < 2; ++a)
        af[a] = *(const bf8*)&Bl[(a * 16 + i) * BS + h * 32 + g * 8];
#pragma unroll
      for (int a = 0; a < 2; ++a)
#pragma unroll
        for (int b = 0; b < 2; ++b)
          acc[a][b] = __builtin_amdgcn_mfma_f32_16x16x32_bf16(wf[b][h], af[a], acc[a][b], 0, 0, 0);
    }
  }

#pragma unroll
  for (int a = 0; a < 2; ++a)
#pragma unroll
    for (int b = 0; b < 2; ++b) {
      const int n = n0 + a * 16 + i;
      const int c = wm * 32 + b * 16 + 4 * g;
      us4 pk = {f2bf(acc[a][b][0]), f2bf(acc[a][b][1]), f2bf(acc[a][b][2]), f2bf(acc[a][b][3])};
      *(us4*)(y1T + ((size_t)(bb << 10) + n) * 128 + c) = pk;
    }

#pragma unroll
  for (int b = 0; b < 2; ++b) {
    float sb[4], qb[4];
#pragma unroll
    for (int r = 0; r < 4; ++r) {
      float v0 = b2f(f2bf(acc[0][b][r]));
      float v1 = b2f(f2bf(acc[1][b][r]));
      sb[r] = v0 + v1;
      qb[r] = v0 * v0 + v1 * v1;
    }
#pragma unroll
    for (int o = 1; o < 16; o <<= 1) {
#pragma unroll
      for (int r = 0; r < 4; ++r) {
        sb[r] += __shfl_xor(sb[r], o);
        qb[r] += __shfl_xor(qb[r], o);
      }
    }
    if (i == 0) {
#pragma unroll
      for (int r = 0; r < 4; ++r) {
        const int c = wm * 32 + b * 16 + 4 * g + r;
        Sl[c] = sb[r];
        Ql[c] = qb[r];
      }
    }
  }

  __syncthreads();
  const int blk = bb * 32 + blockIdx.x;      // 0..511
  if (tid < 128) {
    pS1[(size_t)tid * 512 + blk] = Sl[tid];
    pQ1[(size_t)tid * 512 + blk] = Ql[tid];
  }
}

// 128 blocks x 64 threads: reduce 512 partials per channel -> scl1/sht1.
__global__ __launch_bounds__(64) void k_bnfin1(const float* __restrict__ pS1,
                                               const float* __restrict__ pQ1,
                                               const float* __restrict__ g,
                                               const float* __restrict__ be,
                                               float* __restrict__ scl,
                                               float* __restrict__ sht) {
  const int c = blockIdx.x, t = threadIdx.x;
  float S = 0.f, Q = 0.f;
#pragma unroll
  for (int k = 0; k < 8; ++k) {
    S += pS1[(size_t)c * 512 + t + k * 64];
    Q += pQ1[(size_t)c * 512 + t + k * 64];
  }
#pragma unroll
  for (int o = 32; o > 0; o >>= 1) {
    S += __shfl_down(S, o);
    Q += __shfl_down(Q, o);
  }
  if (t == 0) {
    const float inv_n = 1.f / 16384.f;
    const float mean = S * inv_n, var = Q * inv_n - mean * mean;
    const float sc = rsqrtf(var + 1e-5f) * g[c];
    scl[c] = sc;
    sht[c] = be[c] - mean * sc;
  }
}

// ---------------------------------------------------------------------------
// qkv GEMM: stage y1T tile ONCE (bn1+relu fused), compute q,k,v against it.
// grid (8, 2, 16); blockIdx.y = half (64-channel half of each of q/k/v).
// ---------------------------------------------------------------------------
__global__ __launch_bounds__(256) void k_qkv(const unsigned short* __restrict__ W,
                                             const unsigned short* __restrict__ Bact,
                                             const float* __restrict__ scl,
                                             const float* __restrict__ sht,
                                             const float* __restrict__ rw,
                                             const float* __restrict__ rh,
                                             unsigned short* __restrict__ out0,
                                             unsigned short* __restrict__ out1,
                                             unsigned short* __restrict__ out2) {
  constexpr int BS = 136;
  __shared__ unsigned short Blds[128 * BS];
  __shared__ float scl_s[128], sht_s[128];

  const int bb = blockIdx.z, half = blockIdx.y;
  const int n0 = blockIdx.x * 128;
  const int tid = threadIdx.x, lane = tid & 63, wv = tid >> 6;
  const int wn = wv & 1, wm = wv >> 1;
  const int i = lane & 15, g = lane >> 4;

  const unsigned short* Bp = Bact + ((size_t)bb * NQ + n0) * 128;

  const int sn = tid >> 1;
  const int sk = (tid & 1) * 8;

  if (tid < 128) { scl_s[tid] = scl[tid]; sht_s[tid] = sht[tid]; }

  auto loadw = [&](bf8 (&wf)[2][4], int typ) {
    const int m0 = typ * 128 + half * 64;
#pragma unroll
    for (int b = 0; b < 2; ++b)
#pragma unroll
      for (int h = 0; h < 4; ++h)
        wf[b][h] = *(const bf8*)(W + (size_t)(m0 + wm * 32 + b * 16 + i) * 128 + h * 32 + g * 8);
  };

  bf8 wf0[2][4], wf1[2][4];
  loadw(wf0, 0);
  __syncthreads();                        // scl_s ready

#pragma unroll
  for (int p = 0; p < 8; ++p) {
    us8 v = *(const us8*)(Bp + (size_t)sn * 128 + sk + p * 16);
    const int kb = sk + p * 16;
    float scv[8], shv[8];
    *(float4*)scv = *(const float4*)&scl_s[kb];
    *(float4*)(scv + 4) = *(const float4*)&scl_s[kb + 4];
    *(float4*)shv = *(const float4*)&sht_s[kb];
    *(float4*)(shv + 4) = *(const float4*)&sht_s[kb + 4];
#pragma unroll
    for (int j = 0; j < 8; ++j)
      v[j] = f2bf(fmaxf(fmaf(b2f(v[j]), scv[j], shv[j]), 0.f));
    *(us8*)(&Blds[sn * BS + sk + p * 16]) = v;
  }
  __syncthreads();

  f32x4 acc[4][2];

  auto gemmWA = [&](bf8 (&wf)[2][4]) {    // D = W * act  (c-run, n-lane)
#pragma unroll
    for (int a = 0; a < 4; ++a)
#pragma unroll
      for (int b = 0; b < 2; ++b) acc[a][b] = {0.f, 0.f, 0.f, 0.f};
#pragma unroll
    for (int h = 0; h < 4; ++h) {
      bf8 af[4];
#pragma unroll
      for (int a = 0; a < 4; ++a)
        af[a] = *(const bf8*)&Blds[(wn * 64 + a * 16 + i) * BS + h * 32 + g * 8];
#pragma unroll
      for (int a = 0; a < 4; ++a)
#pragma unroll
        for (int b = 0; b < 2; ++b)
          acc[a][b] = __builtin_amdgcn_mfma_f32_16x16x32_bf16(wf[b][h], af[a], acc[a][b], 0, 0, 0);
    }
  };
  auto gemmAW = [&](bf8 (&wf)[2][4]) {    // D = act * W  (n-run, c-lane)
#pragma unroll
    for (int a = 0; a < 4; ++a)
#pragma unroll
      for (int b = 0; b < 2; ++b) acc[a][b] = {0.f, 0.f, 0.f, 0.f};
#pragma unroll
    for (int h = 0; h < 4; ++h) {
      bf8 af[4];
#pragma unroll
      for (int a = 0; a < 4; ++a)
        af[a] = *(const bf8*)&Blds[(wn * 64 + a * 16 + i) * BS + h * 32 + g * 8];
#pragma unroll
      for (int a = 0; a < 4; ++a)
#pragma unroll
        for (int b = 0; b < 2; ++b)
          acc[a][b] = __builtin_amdgcn_mfma_f32_16x16x32_bf16(af[a], wf[b][h], acc[a][b], 0, 0, 0);
    }
  };

  // ---- q ----
  loadw(wf1, 1);
  gemmWA(wf0);
#pragma unroll
  for (int a = 0; a < 4; ++a)
#pragma unroll
    for (int b = 0; b < 2; ++b) {
      const int n = n0 + wn * 64 + a * 16 + i;
      const int c = half * 64 + wm * 32 + b * 16 + 4 * g;
      const int hh = c >> 5, d = c & 31;
      us4 pk = {f2bf(acc[a][b][0] * QSCALE), f2bf(acc[a][b][1] * QSCALE),
                f2bf(acc[a][b][2] * QSCALE), f2bf(acc[a][b][3] * QSCALE)};
      *(us4*)(out0 + (((size_t)(bb * 4 + hh) << 10) + n) * 32 + d) = pk;
    }

  // ---- k ----
  loadw(wf0, 2);
  gemmWA(wf1);
#pragma unroll
  for (int a = 0; a < 4; ++a)
#pragma unroll
    for (int b = 0; b < 2; ++b) {
      const int n = n0 + wn * 64 + a * 16 + i;
      const int c = half * 64 + wm * 32 + b * 16 + 4 * g;
      const int hh = c >> 5, d = c & 31;
      const int wcol = n & 31, hrow = n >> 5;
      float vv[4];
#pragma unroll
      for (int r = 0; r < 4; ++r)
        vv[r] = acc[a][b][r] + rw[(c + r) * 32 + wcol] + rh[(c + r) * 32 + hrow];
      us4 pk = {f2bf(vv[0]), f2bf(vv[1]), f2bf(vv[2]), f2bf(vv[3])};
      *(us4*)(out1 + (((size_t)(bb * 4 + hh) << 10) + n) * 32 + d) = pk;
    }

  // ---- v ----
  gemmAW(wf0);
#pragma unroll
  for (int a = 0; a < 4; ++a)
#pragma unroll
    for (int b = 0; b < 2; ++b) {
      const int c = half * 64 + wm * 32 + b * 16 + i;
      const int nb = n0 + wn * 64 + a * 16 + 4 * g;
      const int hh = c >> 5, dd = c & 31;
      us4 pk = {f2bf(acc[a][b][0]), f2bf(acc[a][b][1]), f2bf(acc[a][b][2]), f2bf(acc[a][b][3])};
      *(us4*)(out2 + (((size_t)(bb * 4 + hh) * 32 + dd) << 10) + nb) = pk;
    }
}

// ---------------------------------------------------------------------------
// MFMA flash attention: 32 queries/wave (2 Q-frags), pipelined K/V staging.
// grid (NQ/128, BATCH*HEADS), 256 threads. Writes fp32 aoT [b][n][128].
// ---------------------------------------------------------------------------
__global__ __launch_bounds__(256) void k_attn_mfma(const unsigned short* __restrict__ qs,
                                                   const unsigned short* __restrict__ kt,
                                                   const unsigned short* __restrict__ vt,
                                                   float* __restrict__ aoT) {
  const int bh   = blockIdx.y;
  const int tid  = threadIdx.x;
  const int lane = tid & 63;
  const int wv   = tid >> 6;
  const int i    = lane & 15;
  const int g    = lane >> 4;
  const int n0w  = blockIdx.x * 128 + wv * 32;

  __shared__ unsigned short Ks[64 * 56];
  __shared__ unsigned short Vt[32 * 72];

  const bf8 qfA = *(const bf8*)(qs + ((size_t)bh * NQ + n0w + i) * 32 + g * 8);
  const bf8 qfB = *(const bf8*)(qs + ((size_t)bh * NQ + n0w + 16 + i) * 32 + g * 8);

  f32x4 o0A = {0.f,0.f,0.f,0.f}, o1A = {0.f,0.f,0.f,0.f};
  f32x4 o0B = {0.f,0.f,0.f,0.f}, o1B = {0.f,0.f,0.f,0.f};
  float mA = -1e30f, lA = 0.f, mB = -1e30f, lB = 0.f;

  const unsigned short* kb = kt + (size_t)bh * NQ * 32;
  const unsigned short* vb = vt + (size_t)bh * 32 * NQ;

  const int skey = tid >> 2, sds = (tid & 3) * 8;
  const int svd  = tid >> 3, svn = (tid & 7) * 8;

  // prologue loads for tile 0
  bf8 kvld = *(const bf8*)(kb + (size_t)skey * 32 + sds);
  bf8 vvld = *(const bf8*)(vb + (size_t)svd * NQ + svn);

  for (int k0 = 0; k0 < NQ; k0 += 64) {
    __syncthreads();
    *(bf8*)&Ks[skey * 56 + sds] = kvld;
    *(bf8*)&Vt[svd * 72 + svn]  = vvld;
    __syncthreads();
    if (k0 + 64 < NQ) {   // issue next-tile loads; latency hides under compute
      kvld = *(const bf8*)(kb + (size_t)(k0 + 64 + skey) * 32 + sds);
      vvld = *(const bf8*)(vb + (size_t)svd * NQ + (k0 + 64) + svn);
    }

    const f32x4 zero = {0.f,0.f,0.f,0.f};
    f32x4 stA[4], stB[4];
#pragma unroll
    for (int t = 0; t < 4; ++t) {
      bf8 kf = *(const bf8*)&Ks[(t * 16 + i) * 56 + g * 8];
      stA[t] = __builtin_amdgcn_mfma_f32_16x16x32_bf16(kf, qfA, zero, 0, 0, 0);
      stB[t] = __builtin_amdgcn_mfma_f32_16x16x32_bf16(kf, qfB, zero, 0, 0, 0);
    }

    // ---- softmax A ----
    unsigned int pkA[4][2], pkB[4][2];
    {
      float tmax = stA[0][0];
#pragma unroll
      for (int t = 0; t < 4; ++t)
#pragma unroll
        for (int r = 0; r < 4; ++r) tmax = fmaxf(tmax, stA[t][r]);
      tmax = fmaxf(tmax, __shfl_xor(tmax, 16));
      tmax = fmaxf(tmax, __shfl_xor(tmax, 32));
      const float mn = fmaxf(mA, tmax);
      const float corr = fast_exp2(mA - mn);
      mA = mn;
      float ps = 0.f;
#pragma unroll
      for (int t = 0; t < 4; ++t) {
        float p0 = fast_exp2(stA[t][0] - mn);
        float p1 = fast_exp2(stA[t][1] - mn);
        float p2 = fast_exp2(stA[t][2] - mn);
        float p3 = fast_exp2(stA[t][3] - mn);
        ps += (p0 + p1) + (p2 + p3);
        unsigned int pa, pb;
        asm("v_cvt_pk_bf16_f32 %0, %1, %2" : "=v"(pa) : "v"(p0), "v"(p1));
        asm("v_cvt_pk_bf16_f32 %0, %1, %2" : "=v"(pb) : "v"(p2), "v"(p3));
        pkA[t][0] = pa; pkA[t][1] = pb;
      }
      ps += __shfl_xor(ps, 16);
      ps += __shfl_xor(ps, 32);
      lA = lA * corr + ps;
#pragma unroll
      for (int r = 0; r < 4; ++r) { o0A[r] *= corr; o1A[r] *= corr; }
    }
    // ---- softmax B ----
    {
      float tmax = stB[0][0];
#pragma unroll
      for (int t = 0; t < 4; ++t)
#pragma unroll
        for (int r = 0; r < 4; ++r) tmax = fmaxf(tmax, stB[t][r]);
      tmax = fmaxf(tmax, __shfl_xor(tmax, 16));
      tmax = fmaxf(tmax, __shfl_xor(tmax, 32));
      const float mn = fmaxf(mB, tmax);
      const float corr = fast_exp2(mB - mn);
      mB = mn;
      float ps = 0.f;
#pragma unroll
      for (int t = 0; t < 4; ++t) {
        float p0 = fast_exp2(stB[t][0] - mn);
        float p1 = fast_exp2(stB[t][1] - mn);
        float p2 = fast_exp2(stB[t][2] - mn);
        float p3 = fast_exp2(stB[t][3] - mn);
        ps += (p0 + p1) + (p2 + p3);
        unsigned int pa, pb;
        asm("v_cvt_pk_bf16_f32 %0, %1, %2" : "=v"(pa) : "v"(p0), "v"(p1));
        asm("v_cvt_pk_bf16_f32 %0, %1, %2" : "=v"(pb) : "v"(p2), "v"(p3));
        pkB[t][0] = pa; pkB[t][1] = pb;
      }
      ps += __shfl_xor(ps, 16);
      ps += __shfl_xor(ps, 32);
      lB = lB * corr + ps;
#pragma unroll
      for (int r = 0; r < 4; ++r) { o0B[r] *= corr; o1B[r] *= corr; }
    }

    // ---- PV (shared vf loads for both halves) ----
    const int src0 = ((g & 1) << 5) + i;
    const int src1 = src0 + 16;
    const bool hi = (g >= 2);
#pragma unroll
    for (int s = 0; s < 2; ++s) {
      int a0 = __shfl((int)pkA[2 * s][0], src0);
      int a1 = __shfl((int)pkA[2 * s][1], src0);
      int a2 = __shfl((int)pkA[2 * s][0], src1);
      int a3 = __shfl((int)pkA[2 * s][1], src1);
      int b0 = __shfl((int)pkA[2 * s + 1][0], src0);
      int b1 = __shfl((int)pkA[2 * s + 1][1], src0);
      int b2 = __shfl((int)pkA[2 * s + 1][0], src1);
      int b3 = __shfl((int)pkA[2 * s + 1][1], src1);
      union { int d[4]; bf8 v; } pfA;
      pfA.d[0] = hi ? b0 : a0;
      pfA.d[1] = hi ? b1 : a1;
      pfA.d[2] = hi ? b2 : a2;
      pfA.d[3] = hi ? b3 : a3;
      int c0 = __shfl((int)pkB[2 * s][0], src0);
      int c1 = __shfl((int)pkB[2 * s][1], src0);
      int c2 = __shfl((int)pkB[2 * s][0], src1);
      int c3 = __shfl((int)pkB[2 * s][1], src1);
      int d0 = __shfl((int)pkB[2 * s + 1][0], src0);
      int d1 = __shfl((int)pkB[2 * s + 1][1], src0);
      int d2 = __shfl((int)pkB[2 * s + 1][0], src1);
      int d3 = __shfl((int)pkB[2 * s + 1][1], src1);
      union { int d[4]; bf8 v; } pfB;
      pfB.d[0] = hi ? d0 : c0;
      pfB.d[1] = hi ? d1 : c1;
      pfB.d[2] = hi ? d2 : c2;
      pfB.d[3] = hi ? d3 : c3;
      bf8 vf0 = *(const bf8*)&Vt[(i)      * 72 + s * 32 + g * 8];
      bf8 vf1 = *(const bf8*)&Vt[(16 + i) * 72 + s * 32 + g * 8];
      o0A = __builtin_amdgcn_mfma_f32_16x16x32_bf16(vf0, pfA.v, o0A, 0, 0, 0);
      o1A = __builtin_amdgcn_mfma_f32_16x16x32_bf16(vf1, pfA.v, o1A, 0, 0, 0);
      o0B = __builtin_amdgcn_mfma_f32_16x16x32_bf16(vf0, pfB.v, o0B, 0, 0, 0);
      o1B = __builtin_amdgcn_mfma_f32_16x16x32_bf16(vf1, pfB.v, o1B, 0, 0, 0);
    }
  }

  const float invA = 1.f / lA;
  const float invB = 1.f / lB;
  float* dstA = aoT + (((size_t)(bh >> 2) << 10) + n0w + i) * 128 + (bh & 3) * 32 + 4 * g;
  float* dstB = aoT + (((size_t)(bh >> 2) << 10) + n0w + 16 + i) * 128 + (bh & 3) * 32 + 4 * g;
  f32x4 pA0 = {o0A[0] * invA, o0A[1] * invA, o0A[2] * invA, o0A[3] * invA};
  f32x4 pA1 = {o1A[0] * invA, o1A[1] * invA, o1A[2] * invA, o1A[3] * invA};
  f32x4 pB0 = {o0B[0] * invB, o0B[1] * invB, o0B[2] * invB, o0B[3] * invB};
  f32x4 pB1 = {o1B[0] * invB, o1B[1] * invB, o1B[2] * invB, o1B[3] * invB};
  *(f32x4*)dstA        = pA0;
  *(f32x4*)(dstA + 16) = pA1;
  *(f32x4*)dstB        = pB0;
  *(f32x4*)(dstB + 16) = pB1;
}

// ---------------------------------------------------------------------------
// conv2 stats pass: split-precision MFMA, NO y2 store; bn2 per-block partials.
// Block 64n x 256m (4 m-subtiles), 4 waves. grid (16, 2, 16).
// ---------------------------------------------------------------------------
__global__ __launch_bounds__(256) void k_stat2(const unsigned short* __restrict__ W,
                                               const float* __restrict__ Aof,
                                               float* __restrict__ pBS,
                                               float* __restrict__ pBQ) {
  constexpr int BS = 264;
  __shared__ unsigned short Blds[64 * BS];
  __shared__ float Sl[256], Ql[256];
  const int bb = blockIdx.z;
  const int mh = blockIdx.y;
  const int n0 = blockIdx.x * 64;
  const int tid = threadIdx.x, lane = tid & 63, wv = tid >> 6;
  const int wn = wv & 1, wm = wv >> 1;
  const int i = lane & 15, g = lane >> 4;

  Sl[tid] = 0.f; Ql[tid] = 0.f;

  const int sn = tid >> 2, sk = (tid & 3) * 32;
  const float* src = Aof + (((size_t)(bb << 10)) + n0 + sn) * 128 + sk;
#pragma unroll
  for (int p = 0; p < 4; ++p) {
    float4 f0 = *(const float4*)(src + p * 8);
    float4 f1 = *(const float4*)(src + p * 8 + 4);
    float fv[8] = {f0.x, f0.y, f0.z, f0.w, f1.x, f1.y, f1.z, f1.w};
    us8 hi, lo;
#pragma unroll
    for (int j = 0; j < 8; ++j) {
      unsigned short h16 = f2bf(fv[j]);
      hi[j] = h16;
      lo[j] = f2bf(fv[j] - b2f(h16));
    }
    *(us8*)&Blds[sn * BS + sk + p * 8]       = hi;
    *(us8*)&Blds[sn * BS + 128 + sk + p * 8] = lo;
  }
  __syncthreads();

  auto loadw = [&](bf8 (&wf)[2][4], int lp) {
    const int mt = mh * 4 + lp;
#pragma unroll
    for (int b = 0; b < 2; ++b)
#pragma unroll
      for (int h = 0; h < 4; ++h)
        wf[b][h] = *(const bf8*)(W + (size_t)(mt * 64 + wm * 32 + b * 16 + i) * 128 + h * 32 + g * 8);
  };

  auto step = [&](bf8 (&wf)[2][4], int lp) {
    f32x4 acc[2][2];
#pragma unroll
    for (int a = 0; a < 2; ++a)
#pragma unroll
      for (int b = 0; b < 2; ++b) acc[a][b] = {0.f, 0.f, 0.f, 0.f};
#pragma unroll
    for (int h = 0; h < 4; ++h) {
      bf8 ah[2], al[2];
#pragma unroll
      for (int a = 0; a < 2; ++a) {
        ah[a] = *(const bf8*)&Blds[(wn * 32 + a * 16 + i) * BS + h * 32 + g * 8];
        al[a] = *(const bf8*)&Blds[(wn * 32 + a * 16 + i) * BS + 128 + h * 32 + g * 8];
      }
#pragma unroll
      for (int a = 0; a < 2; ++a)
#pragma unroll
        for (int b = 0; b < 2; ++b) {
          acc[a][b] = __builtin_amdgcn_mfma_f32_16x16x32_bf16(ah[a], wf[b][h], acc[a][b], 0, 0, 0);
          acc[a][b] = __builtin_amdgcn_mfma_f32_16x16x32_bf16(al[a], wf[b][h], acc[a][b], 0, 0, 0);
        }
    }
#pragma unroll
    for (int b = 0; b < 2; ++b) {
      float s = 0.f, q = 0.f;
#pragma unroll
      for (int a = 0; a < 2; ++a)
#pragma unroll
        for (int r = 0; r < 4; ++r) {
          float v = acc[a][b][r];
          s += v; q += v * v;
        }
      s += __shfl_xor(s, 16); s += __shfl_xor(s, 32);
      q += __shfl_xor(q, 16); q += __shfl_xor(q, 32);
      if ((lane & 48) == 0) {
        const int cl = lp * 64 + wm * 32 + b * 16 + i;
        atomicAdd(&Sl[cl], s);
        atomicAdd(&Ql[cl], q);
      }
    }
  };

  bf8 wfA[2][4], wfB[2][4];
  loadw(wfA, 0);
  loadw(wfB, 1);
  step(wfA, 0);
  loadw(wfA, 2);
  step(wfB, 1);
  loadw(wfB, 3);
  step(wfA, 2);
  step(wfB, 3);

  __syncthreads();
  const int pidx = bb * 16 + blockIdx.x;
  pBS[(size_t)(mh * 256 + tid) * 256 + pidx] = Sl[tid];
  pBQ[(size_t)(mh * 256 + tid) * 256 + pidx] = Ql[tid];
}

// 512 blocks x 64 threads: reduce 256 partials per channel.
__global__ __launch_bounds__(64) void k_bnfin2(const float* __restrict__ pBS,
                                               const float* __restrict__ pBQ,
                                               const float* __restrict__ g,
                                               const float* __restrict__ be,
                                               float* __restrict__ scl,
                                               float* __restrict__ sht) {
  const int c = blockIdx.x, t = threadIdx.x;
  float S = 0.f, Q = 0.f;
#pragma unroll
  for (int k = 0; k < 4; ++k) {
    S += pBS[(size_t)c * 256 + t + k * 64];
    Q += pBQ[(size_t)c * 256 + t + k * 64];
  }
#pragma unroll
  for (int o = 32; o > 0; o >>= 1) {
    S += __shfl_down(S, o);
    Q += __shfl_down(Q, o);
  }
  if (t == 0) {
    const float inv_n = 1.f / 16384.f;
    const float mean = S * inv_n, var = Q * inv_n - mean * mean;
    const float sc = rsqrtf(var + 1e-5f) * g[c];
    scl[c] = sc;
    sht[c] = be[c] - mean * sc;
  }
}

// ---------------------------------------------------------------------------
// final pass: recompute conv2 (identical staging/MFMA order as k_stat2),
// apply bn2 + residual + relu, write out. grid (16, 2, 16).
// ---------------------------------------------------------------------------
__global__ __launch_bounds__(256) void k_final2(const unsigned short* __restrict__ W,
                                                const float* __restrict__ Aof,
                                                const float* __restrict__ x,
                                                const float* __restrict__ scl2,
                                                const float* __restrict__ sht2,
                                                float* __restrict__ out) {
  constexpr int BS = 264;
  __shared__ unsigned short Blds[64 * BS];
  __shared__ float scl_s[256], sht_s[256];
  const int bb = blockIdx.z;
  const int mh = blockIdx.y;
  const int n0 = blockIdx.x * 64;
  const int tid = threadIdx.x, lane = tid & 63, wv = tid >> 6;
  const int wn = wv & 1, wm = wv >> 1;
  const int i = lane & 15, g = lane >> 4;

  scl_s[tid] = scl2[mh * 256 + tid];
  sht_s[tid] = sht2[mh * 256 + tid];

  const int sn = tid >> 2, sk = (tid & 3) * 32;
  const float* src = Aof + (((size_t)(bb << 10)) + n0 + sn) * 128 + sk;
#pragma unroll
  for (int p = 0; p < 4; ++p) {
    float4 f0 = *(const float4*)(src + p * 8);
    float4 f1 = *(const float4*)(src + p * 8 + 4);
    float fv[8] = {f0.x, f0.y, f0.z, f0.w, f1.x, f1.y, f1.z, f1.w};
    us8 hi, lo;
#pragma unroll
    for (int j = 0; j < 8; ++j) {
      unsigned short h16 = f2bf(fv[j]);
      hi[j] = h16;
      lo[j] = f2bf(fv[j] - b2f(h16));
    }
    *(us8*)&Blds[sn * BS + sk + p * 8]       = hi;
    *(us8*)&Blds[sn * BS + 128 + sk + p * 8] = lo;
  }
  __syncthreads();

  auto loadw = [&](bf8 (&wf)[2][4], int lp) {
    const int mt = mh * 4 + lp;
#pragma unroll
    for (int b = 0; b < 2; ++b)
#pragma unroll
      for (int h = 0; h < 4; ++h)
        wf[b][h] = *(const bf8*)(W + (size_t)(mt * 64 + wm * 32 + b * 16 + i) * 128 + h * 32 + g * 8);
  };

  auto step = [&](bf8 (&wf)[2][4], int lp) {
    const int mt = mh * 4 + lp;
    f32x4 acc[2][2];
#pragma unroll
    for (int a = 0; a < 2; ++a)
#pragma unroll
      for (int b = 0; b < 2; ++b) acc[a][b] = {0.f, 0.f, 0.f, 0.f};
#pragma unroll
    for (int h = 0; h < 4; ++h) {
      bf8 ah[2], al[2];
#pragma unroll
      for (int a = 0; a < 2; ++a) {
        ah[a] = *(const bf8*)&Blds[(wn * 32 + a * 16 + i) * BS + h * 32 + g * 8];
        al[a] = *(const bf8*)&Blds[(wn * 32 + a * 16 + i) * BS + 128 + h * 32 + g * 8];
      }
#pragma unroll
      for (int a = 0; a < 2; ++a)
#pragma unroll
        for (int b = 0; b < 2; ++b) {
          acc[a][b] = __builtin_amdgcn_mfma_f32_16x16x32_bf16(ah[a], wf[b][h], acc[a][b], 0, 0, 0);
          acc[a][b] = __builtin_amdgcn_mfma_f32_16x16x32_bf16(al[a], wf[b][h], acc[a][b], 0, 0, 0);
        }
    }
#pragma unroll
    for (int a = 0; a < 2; ++a)
#pragma unroll
      for (int b = 0; b < 2; ++b) {
        const int c = mt * 64 + wm * 32 + b * 16 + i;
        const int cl = lp * 64 + wm * 32 + b * 16 + i;
        const int nb = n0 + wn * 32 + a * 16 + 4 * g;
        const float sc = scl_s[cl], sh = sht_s[cl];
        const size_t off = (((size_t)(bb * 512 + c)) << 10) + nb;
        float4 xv = *(const float4*)(x + off);
        f32x4 o;
        o[0] = fmaxf(acc[a][b][0] * sc + sh + xv.x, 0.f);
        o[1] = fmaxf(acc[a][b][1] * sc + sh + xv.y, 0.f);
        o[2] = fmaxf(acc[a][b][2] * sc + sh + xv.z, 0.f);
        o[3] = fmaxf(acc[a][b][3] * sc + sh + xv.w, 0.f);
        *(f32x4*)(out + off) = o;
      }
  };

  bf8 wfA[2][4], wfB[2][4];
  loadw(wfA, 0);
  loadw(wfB, 1);
  step(wfA, 0);
  loadw(wfA, 2);
  step(wfB, 1);
  loadw(wfB, 3);
  step(wfA, 2);
  step(wfB, 3);
}

// ---------------------------------------------------------------------------
extern "C" void kernel_launch(void* const* d_in, const int* in_sizes, int n_in,
                              void* d_out, int out_size, void* d_ws, size_t ws_size,
                              hipStream_t stream) {
  (void)in_sizes; (void)n_in; (void)out_size; (void)ws_size;
  const float* x    = (const float*)d_in[0];
  const float* w1   = (const float*)d_in[1];
  const float* g1   = (const float*)d_in[2];
  const float* b1   = (const float*)d_in[3];
  const float* wqkv = (const float*)d_in[4];
  const float* rw   = (const float*)d_in[5];
  const float* rh   = (const float*)d_in[6];
  const float* w2   = (const float*)d_in[7];
  const float* g2   = (const float*)d_in[8];
  const float* b2   = (const float*)d_in[9];
  float* out = (float*)d_out;
  char* base = (char*)d_ws;

  // Workspace (bytes): aoT fp32 [0,8M) | y1T [8,12) | qs [12,16) | kt [16,20)
  // | vt [20,24) | weights bf16 [24M,+352K) | partials/scalars [25M..26.7M)
  float*          aoT = (float*)(base);
  unsigned short* y1T = (unsigned short*)(base + (8u  << 20));
  unsigned short* qs  = (unsigned short*)(base + (12u << 20));
  unsigned short* kt  = (unsigned short*)(base + (16u << 20));
  unsigned short* vt  = (unsigned short*)(base + (20u << 20));
  unsigned short* wb1 = (unsigned short*)(base + (24u << 20));
  unsigned short* wbq = wb1 + 65536;
  unsigned short* wb2 = wbq + 49152;
  float* pS1  = (float*)(base + (25u << 20));  // 128*512
  float* pQ1  = pS1 + 65536;
  float* pBS  = pQ1 + 65536;                   // 512*256
  float* pBQ  = pBS + 131072;
  float* scl1 = pBQ + 131072;
  float* sht1 = scl1 + 128;
  float* scl2 = sht1 + 128;
  float* sht2 = scl2 + 512;

  // 1) weights -> bf16
  k_wcvt<<<88, 256, 0, stream>>>(w1, wqkv, w2, wb1, wbq, wb2);
  // 2) conv1 (fused transpose + bn1 partials), 512 blocks for occupancy
  k_conv1<<<dim3(32, 1, BATCH), 256, 0, stream>>>(x, wb1, y1T, pS1, pQ1);
  // 3) bn1 finalize
  k_bnfin1<<<128, 64, 0, stream>>>(pS1, pQ1, g1, b1, scl1, sht1);
  // 4) qkv (MFMA, bn1+relu fused, single-staged) -> q,k'(+r),v bf16
  k_qkv<<<dim3(8, 2, BATCH), 256, 0, stream>>>(wbq, y1T, scl1, sht1,
                                               rw, rh, qs, kt, vt);
  // 5) flash attention (32 q/wave, pipelined) -> aoT fp32 [b][n][128]
  k_attn_mfma<<<dim3(NQ / 128, BATCH * 4), 256, 0, stream>>>(qs, kt, vt, aoT);
  // 6) conv2 stats pass (no y2) -> pBS/pBQ
  k_stat2<<<dim3(16, 2, BATCH), 256, 0, stream>>>(wb2, aoT, pBS, pBQ);
  // 7) bn2 finalize
  k_bnfin2<<<512, 64, 0, stream>>>(pBS, pBQ, g2, b2, scl2, sht2);
  // 8) final: recompute conv2 + bn2 + residual + relu -> out
  k_final2<<<dim3(16, 2, BATCH), 256, 0, stream>>>(wb2, aoT, x, scl2, sht2, out);
}